// Round 9
// baseline (366.624 us; speedup 1.0000x reference)
//
#include <hip/hip_runtime.h>

#define NLAGC 20
#define NTC   100
#define DTC   0.01f
#define MU1C  0.06f
#define MU2C  0.02f
#define RC    0.02f
#define SIGC  0.2f
#define BETAC 0.05f
#define ETAC  0.5f
#define EPSC  1e-6f
#define UPENC 100.0f
#define YDECC 0.99004983374916805f   /* exp(-0.01) */
#define FDISCC 0.95122942450071403f  /* exp(-0.05) */
#define GEOMC 0.0081465072f          /* (1-exp(-0.01))*exp(-0.2) */

#define SPB 8     // samples per block (M-tile rows 8..15 phantom)
#define TPB 512   // 8 waves
#define NKT 4     // K tiles of 32 over h (K=128)
#define ZROWS 16  // MFMA M rows in zbuf (8 real + 8 phantom)
#define ZSTR 136  // z row stride in bf16 (128 h + 8 pad)

typedef __attribute__((ext_vector_type(8))) short short8v;
typedef __attribute__((ext_vector_type(4))) float f32x4;

__device__ __forceinline__ float sigm(float x){ return __builtin_amdgcn_rcpf(1.0f+__expf(-x)); }
__device__ __forceinline__ float tanhr(float x){ return 1.0f-2.0f*__builtin_amdgcn_rcpf(1.0f+__expf(2.0f*x)); }
__device__ __forceinline__ unsigned short f2bf(float f){            // RNE (staging)
    unsigned u=__float_as_uint(f);
    u += 0x7fffu + ((u>>16)&1u);
    return (unsigned short)(u>>16);
}
__device__ __forceinline__ unsigned short f2bf_rna(float f){        // 2-inst hot-path pack
    return (unsigned short)((__float_as_uint(f)+0x8000u)>>16);
}

// Register diet vs round 8: pi is computed WITHOUT MFMA (no bpif B-frags, no a4
// accumulator): end-of-step shfl reduce of h*wpi -> per-wave partials in LDS;
// wave 0 sums 8 floats at the next step. Target: total (VGPR+AGPR) <= 128 so
// two 8-wave blocks co-reside (grid=512, 2 blocks/CU).
__global__ __launch_bounds__(TPB,2) void polstm(
    const float* __restrict__ dw,  const float* __restrict__ xin,
    const float* __restrict__ Wf,  const float* __restrict__ bfp,
    const float* __restrict__ Wi,  const float* __restrict__ bip,
    const float* __restrict__ Wo,  const float* __restrict__ bop,
    const float* __restrict__ Wc,  const float* __restrict__ bcp,
    const float* __restrict__ Wpi, const float* __restrict__ bpi,
    float* __restrict__ out)
{
    __shared__ __align__(16) unsigned short zbuf[2][ZROWS*ZSTR];  // 8704 B h double-buffer
    __shared__ float dwl[SPB*NTC];                                // 3200 B
    __shared__ float xl[SPB*21];                                  // 672 B
    __shared__ __align__(16) float pib[2][8][SPB];                // 512 B pi partials [p][wave][row]
    __shared__ __align__(16) float xcur[ZROWS];                   // current x, f32

    const int tid=threadIdx.x, w=tid>>6, lane=tid&63, col=lane&15, kg=lane>>4;
    const int j=w*16+col;                // hidden unit owned by this lane
    const int base=blockIdx.x*SPB;
    const int wid=__builtin_amdgcn_readfirstlane(tid)>>6;   // scalar wave id -> real branches

    for(int e=tid;e<2*ZROWS*ZSTR;e+=TPB) ((unsigned short*)zbuf)[e]=0;
    for(int e=tid;e<SPB*NTC;e+=TPB) dwl[e]=dw[base*NTC+e];
    for(int e=tid;e<SPB*21;e+=TPB)  xl[e]=xin[base*21+e];
    if(tid<ZROWS) xcur[tid]=0.f;         // phantom rows read x=0 forever

    // ---- weights -> register B-fragments (once) ----
    short8v bw[4][NKT];
    float wx[4], wt[4], bg[4];
    #pragma unroll
    for(int g=0;g<4;++g){
        const float* Wp=(g==0)?Wf:(g==1)?Wi:(g==2)?Wo:Wc;
        const float* bv=(g==0)?bfp:(g==1)?bip:(g==2)?bop:bcp;
        wx[g]=Wp[j]; wt[g]=Wp[129*128+j]; bg[g]=bv[j];
        #pragma unroll
        for(int kt=0;kt<NKT;++kt){
            short8v f;
            #pragma unroll
            for(int i=0;i<8;++i) f[i]=(short)f2bf(Wp[(1+kt*32+kg*8+i)*128+j]);
            bw[g][kt]=f;
        }
    }
    const float wp0=Wpi[2*j], wp1=Wpi[2*j+1];
    const float bp0=bpi[0], bp1=bpi[1];

    __syncthreads();                     // LDS staged

    // ---- per-lane state (phantom rows replicate sample row&7, stay finite) ----
    float C[4];
    #pragma unroll
    for(int r=0;r<4;++r){
        int srow=(kg*4+r)&(SPB-1);
        C[r]=(j==0)?xl[srow*21]:0.0f;
    }

    float xs=0.f, ys=0.f, rew=0.f;       // wave 0, lane l<8 owns sample l
    if(wid==0){
        if(lane<SPB){
            float x0=xl[lane*21];
            xs=xl[lane*21+20];
            float acc=0.f;
            #pragma unroll
            for(int i=0;i<NLAGC;++i) acc+=__expf(-DTC*(float)(NLAGC-i))*xl[lane*21+1+i];
            ys=acc*DTC+GEOMC*x0;
        }
    }
    if(j==0){                            // h0 = [x0, 0...0] for real rows
        #pragma unroll
        for(int r=0;r<4;++r){
            int row=kg*4+r;
            if(row<SPB) zbuf[0][row*ZSTR+0]=f2bf(xl[row*21]);
        }
    }

    unsigned short* zr=zbuf[0];
    unsigned short* zw=zbuf[1];

    // ---- init phase: 20 steps, 1 barrier each ----
    #pragma unroll 1
    for(int m=0;m<NLAGC;++m){
        __syncthreads();
        short8v av[NKT];
        {   const unsigned short* zp=zr+col*ZSTR+kg*8;
            #pragma unroll
            for(int kt=0;kt<NKT;++kt) av[kt]=*(const short8v*)(zp+kt*32);
        }
        float tval=(float)(m-NLAGC)*DTC;
        float xr0=xl[(((kg*4+0)&(SPB-1)))*21+1+m], xr1=xl[(((kg*4+1)&(SPB-1)))*21+1+m];
        float xr2=xl[(((kg*4+2)&(SPB-1)))*21+1+m], xr3=xl[(((kg*4+3)&(SPB-1)))*21+1+m];
        float b0=fmaf(wt[0],tval,bg[0]), b1=fmaf(wt[1],tval,bg[1]);
        float b2=fmaf(wt[2],tval,bg[2]), b3=fmaf(wt[3],tval,bg[3]);
        f32x4 a0={fmaf(wx[0],xr0,b0),fmaf(wx[0],xr1,b0),fmaf(wx[0],xr2,b0),fmaf(wx[0],xr3,b0)};
        f32x4 a1={fmaf(wx[1],xr0,b1),fmaf(wx[1],xr1,b1),fmaf(wx[1],xr2,b1),fmaf(wx[1],xr3,b1)};
        f32x4 a2={fmaf(wx[2],xr0,b2),fmaf(wx[2],xr1,b2),fmaf(wx[2],xr2,b2),fmaf(wx[2],xr3,b2)};
        f32x4 a3={fmaf(wx[3],xr0,b3),fmaf(wx[3],xr1,b3),fmaf(wx[3],xr2,b3),fmaf(wx[3],xr3,b3)};
        #pragma unroll
        for(int kt=0;kt<NKT;++kt){
            a0=__builtin_amdgcn_mfma_f32_16x16x32_bf16(av[kt],bw[0][kt],a0,0,0,0);
            a1=__builtin_amdgcn_mfma_f32_16x16x32_bf16(av[kt],bw[1][kt],a1,0,0,0);
            a2=__builtin_amdgcn_mfma_f32_16x16x32_bf16(av[kt],bw[2][kt],a2,0,0,0);
            a3=__builtin_amdgcn_mfma_f32_16x16x32_bf16(av[kt],bw[3][kt],a3,0,0,0);
        }
        #pragma unroll
        for(int r=0;r<4;++r){
            C[r]=C[r]*sigm(a0[r])+tanhr(a3[r])*sigm(a1[r]);
            float h=sigm(a2[r])*tanhr(C[r]);
            zw[(kg*4+r)*ZSTR+j]=f2bf_rna(h);
        }
        unsigned short* tp=zr; zr=zw; zw=tp;
    }
    // x for main step 0
    if(wid==0){ if(lane<SPB) xcur[lane]=xs; }

    // ---- main phase: 100 steps, 2 barriers each ----
    #pragma unroll 1
    for(int t=0;t<NTC;++t){
        __syncthreads();                             // barrier1: zr + pib(t-1) ready
        // wave 0: SDE for step t-1 (pi = sum of 8 partials) -> x_t, write xcur.
        // No MFMA dependency: runs immediately, overlapped by other waves' gates.
        if(wid==0 && t>0){
            if(lane<SPB){
                float p0=bp0, p1=bp1;
                #pragma unroll
                for(int ww=0;ww<8;++ww){ p0+=pib[0][ww][lane]; p1+=pib[1][ww][lane]; }
                p0=2.0f*sigm(p0);
                p1=2.0f*sigm(p1);
                float disc=__expf(-BETAC*(float)(t-1)*DTC);
                float ir=__logf(fmaxf(p0*xs,0.f)+EPSC)*disc-fmaxf(-xs,0.f)*UPENC;
                rew+=ir*DTC;
                float dxv=((MU1C-RC)*p1-p0+RC)*xs+MU2C*ys;
                xs=xs+dxv*DTC+SIGC*xs*p1*dwl[lane*NTC+(t-1)];
                ys=ys*YDECC+xs*DTC;
                xcur[lane]=xs;
            }
        }
        short8v av[NKT];
        {   const unsigned short* zp=zr+col*ZSTR+kg*8;
            #pragma unroll
            for(int kt=0;kt<NKT;++kt) av[kt]=*(const short8v*)(zp+kt*32);
        }
        // all waves: gate MFMAs on h-part (independent of x)
        float tval=(float)t*DTC;
        float tb0=fmaf(wt[0],tval,bg[0]), tb1=fmaf(wt[1],tval,bg[1]);
        float tb2=fmaf(wt[2],tval,bg[2]), tb3=fmaf(wt[3],tval,bg[3]);
        f32x4 a0={tb0,tb0,tb0,tb0}, a1={tb1,tb1,tb1,tb1};
        f32x4 a2={tb2,tb2,tb2,tb2}, a3={tb3,tb3,tb3,tb3};
        #pragma unroll
        for(int kt=0;kt<NKT;++kt){
            a0=__builtin_amdgcn_mfma_f32_16x16x32_bf16(av[kt],bw[0][kt],a0,0,0,0);
            a1=__builtin_amdgcn_mfma_f32_16x16x32_bf16(av[kt],bw[1][kt],a1,0,0,0);
            a2=__builtin_amdgcn_mfma_f32_16x16x32_bf16(av[kt],bw[2][kt],a2,0,0,0);
            a3=__builtin_amdgcn_mfma_f32_16x16x32_bf16(av[kt],bw[3][kt],a3,0,0,0);
        }
        __syncthreads();                             // barrier2: xcur ready
        f32x4 xv=*(const f32x4*)&xcur[kg*4];
        #pragma unroll
        for(int r=0;r<4;++r){
            a0[r]=fmaf(wx[0],xv[r],a0[r]);
            a1[r]=fmaf(wx[1],xv[r],a1[r]);
            a2[r]=fmaf(wx[2],xv[r],a2[r]);
            a3[r]=fmaf(wx[3],xv[r],a3[r]);
        }
        float c0[4], c1[4];
        #pragma unroll
        for(int r=0;r<4;++r){
            C[r]=C[r]*sigm(a0[r])+tanhr(a3[r])*sigm(a1[r]);
            float h=sigm(a2[r])*tanhr(C[r]);
            zw[(kg*4+r)*ZSTR+j]=f2bf_rna(h);
            c0[r]=h*wp0; c1[r]=h*wp1;
        }
        // 16-col in-wave reduce of pi partials (offsets stay inside the kg group)
        #pragma unroll
        for(int off=1;off<16;off<<=1){
            #pragma unroll
            for(int r=0;r<4;++r){
                c0[r]+=__shfl_xor(c0[r],off,64);
                c1[r]+=__shfl_xor(c1[r],off,64);
            }
        }
        if(col<2 && kg<2){                           // only real rows (kg<2)
            f32x4 v;
            if(col==0){ v[0]=c0[0];v[1]=c0[1];v[2]=c0[2];v[3]=c0[3]; }
            else      { v[0]=c1[0];v[1]=c1[1];v[2]=c1[2];v[3]=c1[3]; }
            *(f32x4*)&pib[col][w][kg*4]=v;
        }
        unsigned short* tp=zr; zr=zw; zw=tp;
    }

    // ---- epilogue: last SDE (step NTC-1) + final utility, wave 0 only ----
    __syncthreads();                                 // pib from t=NTC-1 ready
    if(wid==0){
        if(lane<SPB){
            float p0=bp0, p1=bp1;
            #pragma unroll
            for(int ww=0;ww<8;++ww){ p0+=pib[0][ww][lane]; p1+=pib[1][ww][lane]; }
            p0=2.0f*sigm(p0);
            p1=2.0f*sigm(p1);
            float disc=__expf(-BETAC*(float)(NTC-1)*DTC);
            float ir=__logf(fmaxf(p0*xs,0.f)+EPSC)*disc-fmaxf(-xs,0.f)*UPENC;
            rew+=ir*DTC;
            float dxv=((MU1C-RC)*p1-p0+RC)*xs+MU2C*ys;
            xs=xs+dxv*DTC+SIGC*xs*p1*dwl[lane*NTC+(NTC-1)];
            ys=ys*YDECC+xs*DTC;
            rew+=__logf(fmaxf(xs+ETAC*ys,0.f)+EPSC)*(FDISCC/BETAC)-fmaxf(-xs,0.f)*UPENC;
            out[base+lane]=-rew;
        }
    }
}

extern "C" void kernel_launch(void* const* d_in, const int* in_sizes, int n_in,
                              void* d_out, int out_size, void* d_ws, size_t ws_size,
                              hipStream_t stream){
    const float* dw  = (const float*)d_in[0];
    const float* xin = (const float*)d_in[1];
    const float* Wf  = (const float*)d_in[2];
    const float* bf  = (const float*)d_in[3];
    const float* Wi  = (const float*)d_in[4];
    const float* bi  = (const float*)d_in[5];
    const float* Wo  = (const float*)d_in[6];
    const float* bo  = (const float*)d_in[7];
    const float* Wc  = (const float*)d_in[8];
    const float* bc  = (const float*)d_in[9];
    const float* Wpi = (const float*)d_in[10];
    const float* bpi = (const float*)d_in[11];
    float* out = (float*)d_out;
    int nblk = (out_size + SPB - 1) / SPB;   // 512 -> 2 blocks/CU
    polstm<<<dim3(nblk), dim3(TPB), 0, stream>>>(dw, xin, Wf, bf, Wi, bi, Wo, bo, Wc, bc, Wpi, bpi, out);
}

// Round 10
// 296.232 us; speedup vs baseline: 1.2376x; 1.2376x over previous
//
#include <hip/hip_runtime.h>

#define NLAGC 20
#define NTC   100
#define DTC   0.01f
#define MU1C  0.06f
#define MU2C  0.02f
#define RC    0.02f
#define SIGC  0.2f
#define BETAC 0.05f
#define ETAC  0.5f
#define EPSC  1e-6f
#define UPENC 100.0f
#define YDECC 0.99004983374916805f   /* exp(-0.01) */
#define FDISCC 0.95122942450071403f  /* exp(-0.05) */
#define GEOMC 0.0081465072f          /* (1-exp(-0.01))*exp(-0.2) */

#define CH   8    // samples per chain (2 chains per block = 16 samples)
#define TPB  512  // 8 waves
#define NKT  4    // K tiles of 32 over h (K=128)
#define ZROWS 16  // MFMA M rows (8 real + 8 phantom)
#define ZSTR 136  // z row stride in bf16 (128 h + 8 pad)

typedef __attribute__((ext_vector_type(8))) short short8v;
typedef __attribute__((ext_vector_type(4))) float f32x4;

__device__ __forceinline__ float sigm(float x){ return __builtin_amdgcn_rcpf(1.0f+__expf(-x)); }
__device__ __forceinline__ float tanhr(float x){ return 1.0f-2.0f*__builtin_amdgcn_rcpf(1.0f+__expf(2.0f*x)); }
__device__ __forceinline__ unsigned short f2bf(float f){
    unsigned u=__float_as_uint(f);
    u += 0x7fffu + ((u>>16)&1u);
    return (unsigned short)(u>>16);
}
__device__ __forceinline__ unsigned short f2bf_rna(float f){
    return (unsigned short)((__float_as_uint(f)+0x8000u)>>16);
}

#define GATEMFMA(A0,A1,A2,A3,AV) \
    _Pragma("unroll") \
    for(int kt=0;kt<NKT;++kt){ \
        A0=__builtin_amdgcn_mfma_f32_16x16x32_bf16(AV[kt],bw[0][kt],A0,0,0,0); \
        A1=__builtin_amdgcn_mfma_f32_16x16x32_bf16(AV[kt],bw[1][kt],A1,0,0,0); \
        A2=__builtin_amdgcn_mfma_f32_16x16x32_bf16(AV[kt],bw[2][kt],A2,0,0,0); \
        A3=__builtin_amdgcn_mfma_f32_16x16x32_bf16(AV[kt],bw[3][kt],A3,0,0,0); \
    }

// Dual software-interleaved 8-sample chains per block: chain B's independent
// instructions fill chain A's dependent-latency stalls (2 lockstep waves/SIMD
// expose full chain latency otherwise). 1 barrier per superstep; pi via
// full-per-wave MFMA (no cross-wave exchange); same-wave LDS pib bounce.
__global__ __launch_bounds__(TPB,2) void polstm(
    const float* __restrict__ dw,  const float* __restrict__ xin,
    const float* __restrict__ Wf,  const float* __restrict__ bfp,
    const float* __restrict__ Wi,  const float* __restrict__ bip,
    const float* __restrict__ Wo,  const float* __restrict__ bop,
    const float* __restrict__ Wc,  const float* __restrict__ bcp,
    const float* __restrict__ Wpi, const float* __restrict__ bpi,
    float* __restrict__ out)
{
    __shared__ __align__(16) unsigned short zA[2][ZROWS*ZSTR];  // 8704 B chain A h dbuf
    __shared__ __align__(16) unsigned short zB[2][ZROWS*ZSTR];  // 8704 B chain B h dbuf
    __shared__ float dwl[16*NTC];                               // 6400 B
    __shared__ float xl[16*21];                                 // 1344 B
    __shared__ __align__(16) float pibA[2][CH], pibB[2][CH];    // 128 B pi bounce

    const int tid=threadIdx.x, w=tid>>6, lane=tid&63, col=lane&15, kg=lane>>4;
    const int j=w*16+col;
    const int base=blockIdx.x*16;
    const int wid=__builtin_amdgcn_readfirstlane(tid)>>6;

    for(int e=tid;e<2*ZROWS*ZSTR;e+=TPB){ ((unsigned short*)zA)[e]=0; ((unsigned short*)zB)[e]=0; }
    for(int e=tid;e<16*NTC;e+=TPB) dwl[e]=dw[base*NTC+e];
    for(int e=tid;e<16*21;e+=TPB)  xl[e]=xin[base*21+e];

    // ---- weights -> register fragments (shared by both chains) ----
    short8v bw[4][NKT], bpif[NKT];
    float wx[4], wt[4], bg[4];
    #pragma unroll
    for(int g=0;g<4;++g){
        const float* Wp=(g==0)?Wf:(g==1)?Wi:(g==2)?Wo:Wc;
        const float* bv=(g==0)?bfp:(g==1)?bip:(g==2)?bop:bcp;
        wx[g]=Wp[j]; wt[g]=Wp[129*128+j]; bg[g]=bv[j];
        #pragma unroll
        for(int kt=0;kt<NKT;++kt){
            short8v f;
            #pragma unroll
            for(int i=0;i<8;++i) f[i]=(short)f2bf(Wp[(1+kt*32+kg*8+i)*128+j]);
            bw[g][kt]=f;
        }
    }
    #pragma unroll
    for(int kt=0;kt<NKT;++kt){
        short8v f;
        #pragma unroll
        for(int i=0;i<8;++i){
            int k=kt*32+kg*8+i;
            int idx=k*2+((col<2)?col:0);
            float v=Wpi[idx];
            f[i]=(short)((col<2)?f2bf(v):(unsigned short)0);
        }
        bpif[kt]=f;
    }
    const float bp0=bpi[0], bp1=bpi[1];

    __syncthreads();                     // zeroing + xl/dwl staged

    // ---- per-lane state ----
    float CA[4], CB[4];
    #pragma unroll
    for(int r=0;r<4;++r){
        int sr=(kg*4+r)&(CH-1);
        CA[r]=(j==0)?xl[sr*21]:0.0f;
        CB[r]=(j==0)?xl[(CH+sr)*21]:0.0f;
    }
    float xsA=0.f,ysA=0.f,rewA=0.f, xsB=0.f,ysB=0.f,rewB=0.f;  // lane<8 owns sample lane (all waves, redundant)
    if(lane<CH){
        xsA=xl[lane*21+20]; xsB=xl[(CH+lane)*21+20];
        float aA=0.f, aB=0.f;
        #pragma unroll
        for(int i=0;i<NLAGC;++i){
            float e=__expf(-DTC*(float)(NLAGC-i));
            aA+=e*xl[lane*21+1+i];
            aB+=e*xl[(CH+lane)*21+1+i];
        }
        ysA=aA*DTC+GEOMC*xl[lane*21];
        ysB=aB*DTC+GEOMC*xl[(CH+lane)*21];
    }
    if(j==0){                            // h0 = [x0, 0...0] real rows only
        #pragma unroll
        for(int r=0;r<4;++r){
            int row=kg*4+r;
            if(row<CH){
                zA[0][row*ZSTR]=f2bf(xl[row*21]);
                zB[0][row*ZSTR]=f2bf(xl[(CH+row)*21]);
            }
        }
    }
    __syncthreads();                     // h0 visible

    unsigned short *zrA=zA[0], *zwA=zA[1];
    unsigned short *zrB=zB[0], *zwB=zB[1];

    short8v avA[NKT];
    {   const unsigned short* zp=zrA+col*ZSTR+kg*8;
        #pragma unroll
        for(int kt=0;kt<NKT;++kt) avA[kt]=*(const short8v*)(zp+kt*32);
    }

    // ---- init phase: 20 interleaved supersteps, 1 barrier each ----
    #pragma unroll 1
    for(int m=0;m<NLAGC;++m){
        float tval=(float)(m-NLAGC)*DTC;
        float b0=fmaf(wt[0],tval,bg[0]), b1=fmaf(wt[1],tval,bg[1]);
        float b2=fmaf(wt[2],tval,bg[2]), b3=fmaf(wt[3],tval,bg[3]);
        // A accs (x-lag folded) + MFMA
        f32x4 aA0,aA1,aA2,aA3;
        #pragma unroll
        for(int r=0;r<4;++r){
            float xr=xl[((kg*4+r)&(CH-1))*21+1+m];
            aA0[r]=fmaf(wx[0],xr,b0); aA1[r]=fmaf(wx[1],xr,b1);
            aA2[r]=fmaf(wx[2],xr,b2); aA3[r]=fmaf(wx[3],xr,b3);
        }
        GATEMFMA(aA0,aA1,aA2,aA3,avA);
        // read B
        short8v avB[NKT];
        {   const unsigned short* zp=zrB+col*ZSTR+kg*8;
            #pragma unroll
            for(int kt=0;kt<NKT;++kt) avB[kt]=*(const short8v*)(zp+kt*32);
        }
        // B accs + MFMA
        f32x4 aB0,aB1,aB2,aB3;
        #pragma unroll
        for(int r=0;r<4;++r){
            float xr=xl[(CH+((kg*4+r)&(CH-1)))*21+1+m];
            aB0[r]=fmaf(wx[0],xr,b0); aB1[r]=fmaf(wx[1],xr,b1);
            aB2[r]=fmaf(wx[2],xr,b2); aB3[r]=fmaf(wx[3],xr,b3);
        }
        GATEMFMA(aB0,aB1,aB2,aB3,avB);
        // nonlin A
        #pragma unroll
        for(int r=0;r<4;++r){
            CA[r]=CA[r]*sigm(aA0[r])+tanhr(aA3[r])*sigm(aA1[r]);
            float h=sigm(aA2[r])*tanhr(CA[r]);
            zwA[(kg*4+r)*ZSTR+j]=f2bf_rna(h);
        }
        // nonlin B
        #pragma unroll
        for(int r=0;r<4;++r){
            CB[r]=CB[r]*sigm(aB0[r])+tanhr(aB3[r])*sigm(aB1[r]);
            float h=sigm(aB2[r])*tanhr(CB[r]);
            zwB[(kg*4+r)*ZSTR+j]=f2bf_rna(h);
        }
        __syncthreads();
        unsigned short* tp;
        tp=zrA; zrA=zwA; zwA=tp;
        tp=zrB; zrB=zwB; zwB=tp;
        {   const unsigned short* zp=zrA+col*ZSTR+kg*8;
            #pragma unroll
            for(int kt=0;kt<NKT;++kt) avA[kt]=*(const short8v*)(zp+kt*32);
        }
    }

    // ---- main phase: 100 interleaved supersteps, 1 barrier each ----
    #pragma unroll 1
    for(int t=0;t<NTC;++t){
        float tval=(float)t*DTC;
        float tb0=fmaf(wt[0],tval,bg[0]), tb1=fmaf(wt[1],tval,bg[1]);
        float tb2=fmaf(wt[2],tval,bg[2]), tb3=fmaf(wt[3],tval,bg[3]);
        // A: pi chain first, then gate MFMAs
        f32x4 a4A={0.f,0.f,0.f,0.f};
        #pragma unroll
        for(int kt=0;kt<NKT;++kt)
            a4A=__builtin_amdgcn_mfma_f32_16x16x32_bf16(avA[kt],bpif[kt],a4A,0,0,0);
        f32x4 aA0={tb0,tb0,tb0,tb0}, aA1={tb1,tb1,tb1,tb1};
        f32x4 aA2={tb2,tb2,tb2,tb2}, aA3={tb3,tb3,tb3,tb3};
        GATEMFMA(aA0,aA1,aA2,aA3,avA);
        // read B
        short8v avB[NKT];
        {   const unsigned short* zp=zrB+col*ZSTR+kg*8;
            #pragma unroll
            for(int kt=0;kt<NKT;++kt) avB[kt]=*(const short8v*)(zp+kt*32);
        }
        // B: pi + gates
        f32x4 a4B={0.f,0.f,0.f,0.f};
        #pragma unroll
        for(int kt=0;kt<NKT;++kt)
            a4B=__builtin_amdgcn_mfma_f32_16x16x32_bf16(avB[kt],bpif[kt],a4B,0,0,0);
        f32x4 aB0={tb0,tb0,tb0,tb0}, aB1={tb1,tb1,tb1,tb1};
        f32x4 aB2={tb2,tb2,tb2,tb2}, aB3={tb3,tb3,tb3,tb3};
        GATEMFMA(aB0,aB1,aB2,aB3,avB);
        // pi A bounce (same-wave LDS; identical cross-wave writes benign)
        if(col<2 && kg<2) *(f32x4*)&pibA[col][kg*4]=a4A;
        asm volatile("s_waitcnt lgkmcnt(0)":::"memory");
        // SDE A (step t-1), redundant on every wave
        if(t>0 && lane<CH){
            float p0=2.0f*sigm(pibA[0][lane]+bp0);
            float p1=2.0f*sigm(pibA[1][lane]+bp1);
            float disc=__expf(-BETAC*(float)(t-1)*DTC);
            rewA+=(__logf(fmaxf(p0*xsA,0.f)+EPSC)*disc-fmaxf(-xsA,0.f)*UPENC)*DTC;
            float dxv=((MU1C-RC)*p1-p0+RC)*xsA+MU2C*ysA;
            xsA=xsA+dxv*DTC+SIGC*xsA*p1*dwl[lane*NTC+(t-1)];
            ysA=ysA*YDECC+xsA*DTC;
        }
        // pi B bounce
        if(col<2 && kg<2) *(f32x4*)&pibB[col][kg*4]=a4B;
        asm volatile("s_waitcnt lgkmcnt(0)":::"memory");
        // fold xA + nonlin A + write
        #pragma unroll
        for(int r=0;r<4;++r){
            float xv=__shfl(xsA,kg*4+r,64);          // phantom rows: lanes 8-15 xsA=0
            aA0[r]=fmaf(wx[0],xv,aA0[r]); aA1[r]=fmaf(wx[1],xv,aA1[r]);
            aA2[r]=fmaf(wx[2],xv,aA2[r]); aA3[r]=fmaf(wx[3],xv,aA3[r]);
            CA[r]=CA[r]*sigm(aA0[r])+tanhr(aA3[r])*sigm(aA1[r]);
            float h=sigm(aA2[r])*tanhr(CA[r]);
            zwA[(kg*4+r)*ZSTR+j]=f2bf_rna(h);
        }
        // SDE B (step t-1)
        if(t>0 && lane<CH){
            float p0=2.0f*sigm(pibB[0][lane]+bp0);
            float p1=2.0f*sigm(pibB[1][lane]+bp1);
            float disc=__expf(-BETAC*(float)(t-1)*DTC);
            rewB+=(__logf(fmaxf(p0*xsB,0.f)+EPSC)*disc-fmaxf(-xsB,0.f)*UPENC)*DTC;
            float dxv=((MU1C-RC)*p1-p0+RC)*xsB+MU2C*ysB;
            xsB=xsB+dxv*DTC+SIGC*xsB*p1*dwl[(CH+lane)*NTC+(t-1)];
            ysB=ysB*YDECC+xsB*DTC;
        }
        // fold xB + nonlin B + write
        #pragma unroll
        for(int r=0;r<4;++r){
            float xv=__shfl(xsB,kg*4+r,64);
            aB0[r]=fmaf(wx[0],xv,aB0[r]); aB1[r]=fmaf(wx[1],xv,aB1[r]);
            aB2[r]=fmaf(wx[2],xv,aB2[r]); aB3[r]=fmaf(wx[3],xv,aB3[r]);
            CB[r]=CB[r]*sigm(aB0[r])+tanhr(aB3[r])*sigm(aB1[r]);
            float h=sigm(aB2[r])*tanhr(CB[r]);
            zwB[(kg*4+r)*ZSTR+j]=f2bf_rna(h);
        }
        __syncthreads();
        unsigned short* tp;
        tp=zrA; zrA=zwA; zwA=tp;
        tp=zrB; zrB=zwB; zwB=tp;
        {   const unsigned short* zp=zrA+col*ZSTR+kg*8;
            #pragma unroll
            for(int kt=0;kt<NKT;++kt) avA[kt]=*(const short8v*)(zp+kt*32);
        }
    }

    // ---- epilogue: SDE(NTC-1) + final utility for both chains ----
    {
        f32x4 a4A={0.f,0.f,0.f,0.f};
        #pragma unroll
        for(int kt=0;kt<NKT;++kt)
            a4A=__builtin_amdgcn_mfma_f32_16x16x32_bf16(avA[kt],bpif[kt],a4A,0,0,0);
        short8v avB[NKT];
        {   const unsigned short* zp=zrB+col*ZSTR+kg*8;
            #pragma unroll
            for(int kt=0;kt<NKT;++kt) avB[kt]=*(const short8v*)(zp+kt*32);
        }
        f32x4 a4B={0.f,0.f,0.f,0.f};
        #pragma unroll
        for(int kt=0;kt<NKT;++kt)
            a4B=__builtin_amdgcn_mfma_f32_16x16x32_bf16(avB[kt],bpif[kt],a4B,0,0,0);
        if(col<2 && kg<2){
            *(f32x4*)&pibA[col][kg*4]=a4A;
            *(f32x4*)&pibB[col][kg*4]=a4B;
        }
        asm volatile("s_waitcnt lgkmcnt(0)":::"memory");
        if(lane<CH){
            float disc=__expf(-BETAC*(float)(NTC-1)*DTC);
            {   float p0=2.0f*sigm(pibA[0][lane]+bp0);
                float p1=2.0f*sigm(pibA[1][lane]+bp1);
                rewA+=(__logf(fmaxf(p0*xsA,0.f)+EPSC)*disc-fmaxf(-xsA,0.f)*UPENC)*DTC;
                float dxv=((MU1C-RC)*p1-p0+RC)*xsA+MU2C*ysA;
                xsA=xsA+dxv*DTC+SIGC*xsA*p1*dwl[lane*NTC+(NTC-1)];
                ysA=ysA*YDECC+xsA*DTC;
                rewA+=__logf(fmaxf(xsA+ETAC*ysA,0.f)+EPSC)*(FDISCC/BETAC)-fmaxf(-xsA,0.f)*UPENC;
            }
            {   float p0=2.0f*sigm(pibB[0][lane]+bp0);
                float p1=2.0f*sigm(pibB[1][lane]+bp1);
                rewB+=(__logf(fmaxf(p0*xsB,0.f)+EPSC)*disc-fmaxf(-xsB,0.f)*UPENC)*DTC;
                float dxv=((MU1C-RC)*p1-p0+RC)*xsB+MU2C*ysB;
                xsB=xsB+dxv*DTC+SIGC*xsB*p1*dwl[(CH+lane)*NTC+(NTC-1)];
                ysB=ysB*YDECC+xsB*DTC;
                rewB+=__logf(fmaxf(xsB+ETAC*ysB,0.f)+EPSC)*(FDISCC/BETAC)-fmaxf(-xsB,0.f)*UPENC;
            }
            if(wid==0){
                out[base+lane]=-rewA;
                out[base+CH+lane]=-rewB;
            }
        }
    }
}

extern "C" void kernel_launch(void* const* d_in, const int* in_sizes, int n_in,
                              void* d_out, int out_size, void* d_ws, size_t ws_size,
                              hipStream_t stream){
    const float* dw  = (const float*)d_in[0];
    const float* xin = (const float*)d_in[1];
    const float* Wf  = (const float*)d_in[2];
    const float* bf  = (const float*)d_in[3];
    const float* Wi  = (const float*)d_in[4];
    const float* bi  = (const float*)d_in[5];
    const float* Wo  = (const float*)d_in[6];
    const float* bo  = (const float*)d_in[7];
    const float* Wc  = (const float*)d_in[8];
    const float* bc  = (const float*)d_in[9];
    const float* Wpi = (const float*)d_in[10];
    const float* bpi = (const float*)d_in[11];
    float* out = (float*)d_out;
    int nblk = (out_size + 15) / 16;   // 256 blocks, 1/CU
    polstm<<<dim3(nblk), dim3(TPB), 0, stream>>>(dw, xin, Wf, bf, Wi, bi, Wo, bo, Wc, bc, Wpi, bpi, out);
}

// Round 12
// 195.261 us; speedup vs baseline: 1.8776x; 1.5171x over previous
//
#include <hip/hip_runtime.h>

#define NLAGC 20
#define NTC   100
#define DTC   0.01f
#define MU1C  0.06f
#define MU2C  0.02f
#define RC    0.02f
#define SIGC  0.2f
#define BETAC 0.05f
#define ETAC  0.5f
#define EPSC  1e-6f
#define UPENC 100.0f
#define YDECC 0.99004983374916805f   /* exp(-0.01) */
#define FDISCC 0.95122942450071403f  /* exp(-0.05) */
#define GEOMC 0.0081465072f          /* (1-exp(-0.01))*exp(-0.2) */

#define TPB   1024   // 16 waves -> 4 waves/SIMD co-resident in ONE block
#define ZSTR  136    // z row stride (bf16): 128 h + 8 pad
#define GUS   132    // gacc u-stride in floats: 16 s * 8 (2 half * 4 gates) + 4 pad

typedef __attribute__((ext_vector_type(8))) short short8v;
typedef __attribute__((ext_vector_type(4))) float f32x4;

__device__ __forceinline__ float sigm(float x){ return __builtin_amdgcn_rcpf(1.0f+__expf(-x)); }
__device__ __forceinline__ float tanhr(float x){ return 1.0f-2.0f*__builtin_amdgcn_rcpf(1.0f+__expf(2.0f*x)); }
__device__ __forceinline__ unsigned short f2bf(float f){
    unsigned u=__float_as_uint(f);
    u += 0x7fffu + ((u>>16)&1u);
    return (unsigned short)(u>>16);
}
__device__ __forceinline__ unsigned short f2bf_rna(float f){
    return (unsigned short)((__float_as_uint(f)+0x8000u)>>16);
}

#define MFMA(AV,BV,AC) __builtin_amdgcn_mfma_f32_16x16x32_bf16(AV,BV,AC,0,0,0)

// Phase 1: half-K MFMAs -> raw gate partials to gacc; pi partials (cg==0
// waves ONLY — the k-range depends only on `half`, so other cg waves would
// produce identical copies; round-11 bug was summing those 8 copies).
#define P1() do{ \
    const unsigned short* zp_=zr+col*ZSTR+half*64+kg*8; \
    short8v av0_=*(const short8v*)(zp_); \
    short8v av1_=*(const short8v*)(zp_+32); \
    f32x4 z4_={0.f,0.f,0.f,0.f}; \
    f32x4 a0_=z4_,a1_=z4_,a2_=z4_,a3_=z4_; \
    a0_=MFMA(av0_,bw[0][0],a0_); a1_=MFMA(av0_,bw[1][0],a1_); \
    a2_=MFMA(av0_,bw[2][0],a2_); a3_=MFMA(av0_,bw[3][0],a3_); \
    a0_=MFMA(av1_,bw[0][1],a0_); a1_=MFMA(av1_,bw[1][1],a1_); \
    a2_=MFMA(av1_,bw[2][1],a2_); a3_=MFMA(av1_,bw[3][1],a3_); \
    _Pragma("unroll") \
    for(int r_=0;r_<4;++r_){ \
        f32x4 v_={a0_[r_],a1_[r_],a2_[r_],a3_[r_]}; \
        *(f32x4*)&gacc[j*GUS+(kg*4+r_)*8+half*4]=v_; \
    } \
    if(cg==0){ \
        f32x4 a4_=z4_; \
        a4_=MFMA(av0_,bpif[0],a4_); \
        a4_=MFMA(av1_,bpif[1],a4_); \
        if(col<2) *(f32x4*)&pib[(half*2+col)*16+kg*4]=a4_; \
    } \
}while(0)

// Combine the two K-halves for this thread's 2 cells (dense: 2 cells/thread).
#define COMBINE(PRE) do{ \
    _Pragma("unroll") \
    for(int c_=0;c_<2;++c_){ \
        f32x4 v0_=*(const f32x4*)&gacc[(u0+c_)*GUS+s*8]; \
        f32x4 v1_=*(const f32x4*)&gacc[(u0+c_)*GUS+s*8+4]; \
        _Pragma("unroll") \
        for(int g_=0;g_<4;++g_) PRE[c_][g_]=v0_[g_]+v1_[g_]; \
    } \
}while(0)

// Fold b + wt*t + wx*x, nonlinearity, pack 2 bf16 h values, write to zw.
#define NONLIN(PRE,XV,TV) do{ \
    unsigned hp_=0; \
    _Pragma("unroll") \
    for(int c_=0;c_<2;++c_){ \
        float g0_=fmaf(wx2[0][c_],(XV),fmaf(wt2[0][c_],(TV),PRE[c_][0]+bg2[0][c_])); \
        float g1_=fmaf(wx2[1][c_],(XV),fmaf(wt2[1][c_],(TV),PRE[c_][1]+bg2[1][c_])); \
        float g2_=fmaf(wx2[2][c_],(XV),fmaf(wt2[2][c_],(TV),PRE[c_][2]+bg2[2][c_])); \
        float g3_=fmaf(wx2[3][c_],(XV),fmaf(wt2[3][c_],(TV),PRE[c_][3]+bg2[3][c_])); \
        Creg[c_]=Creg[c_]*sigm(g0_)+tanhr(g3_)*sigm(g1_); \
        float h_=sigm(g2_)*tanhr(Creg[c_]); \
        hp_|=(unsigned)f2bf_rna(h_)<<(16*c_); \
    } \
    *(unsigned*)&zw[s*ZSTR+u0]=hp_; \
}while(0)

__global__ __launch_bounds__(TPB) void polstm(
    const float* __restrict__ dw,  const float* __restrict__ xin,
    const float* __restrict__ Wf,  const float* __restrict__ bfp,
    const float* __restrict__ Wi,  const float* __restrict__ bip,
    const float* __restrict__ Wo,  const float* __restrict__ bop,
    const float* __restrict__ Wc,  const float* __restrict__ bcp,
    const float* __restrict__ Wpi, const float* __restrict__ bpi,
    float* __restrict__ out)
{
    __shared__ __align__(16) float gacc[128*GUS];               // 67,584 B gate exchange
    __shared__ __align__(16) unsigned short zbuf[2][16*ZSTR];   // 8,704 B h double-buffer
    __shared__ float dwl[16*NTC];                               // 6,400 B
    __shared__ float xl[16*21];                                 // 1,344 B
    __shared__ __align__(16) float pib[2*2*16];                 // 256 B pi partials [half][p][s]
    __shared__ float xcur[16];

    const int tid=threadIdx.x, w=tid>>6, lane=tid&63, col=lane&15, kg=lane>>4;
    const int half=w&1, cg=w>>1, j=cg*16+col;    // writer: K-half + 16 unit-cols
    const int s=tid&15, u0=(tid>>4)<<1;          // reader: sample s, cells u0,u0+1
    const int base=blockIdx.x*16;
    const int wid=__builtin_amdgcn_readfirstlane(w);

    for(int e=tid;e<2*16*ZSTR;e+=TPB) ((unsigned short*)zbuf)[e]=0;
    for(int e=tid;e<16*NTC;e+=TPB) dwl[e]=dw[base*NTC+e];
    for(int e=tid;e<16*21;e+=TPB)  xl[e]=xin[base*21+e];

    // ---- writer weights: half-K register B-fragments ----
    short8v bw[4][2], bpif[2];
    #pragma unroll
    for(int g=0;g<4;++g){
        const float* Wp=(g==0)?Wf:(g==1)?Wi:(g==2)?Wo:Wc;
        #pragma unroll
        for(int kt=0;kt<2;++kt){
            short8v f;
            #pragma unroll
            for(int i=0;i<8;++i) f[i]=(short)f2bf(Wp[(1+half*64+kt*32+kg*8+i)*128+j]);
            bw[g][kt]=f;
        }
    }
    #pragma unroll
    for(int kt=0;kt<2;++kt){
        short8v f;
        #pragma unroll
        for(int i=0;i<8;++i){
            int k=half*64+kt*32+kg*8+i;
            float v=Wpi[k*2+((col<2)?col:0)];
            f[i]=(short)((col<2)?f2bf(v):(unsigned short)0);
        }
        bpif[kt]=f;
    }
    // ---- reader constants for this thread's 2 cells ----
    float wx2[4][2], wt2[4][2], bg2[4][2];
    #pragma unroll
    for(int g=0;g<4;++g){
        const float* Wp=(g==0)?Wf:(g==1)?Wi:(g==2)?Wo:Wc;
        const float* bv=(g==0)?bfp:(g==1)?bip:(g==2)?bop:bcp;
        #pragma unroll
        for(int c=0;c<2;++c){
            wx2[g][c]=Wp[u0+c];
            wt2[g][c]=Wp[129*128+u0+c];
            bg2[g][c]=bv[u0+c];
        }
    }
    const float bp0=bpi[0], bp1=bpi[1];

    __syncthreads();                     // staging + zeroing done

    // reader cell state
    float Creg[2];
    Creg[0]=(u0==0)?xl[s*21]:0.0f;
    Creg[1]=0.0f;
    if(tid<16) zbuf[0][tid*ZSTR]=f2bf(xl[tid*21]);   // h0=[x0,0,...]

    // SDE state: wave 0, lane<16 owns sample lane
    float xs=0.f, ys=0.f, rew=0.f;
    if(wid==0 && lane<16){
        float x0=xl[lane*21];
        xs=xl[lane*21+20];
        float acc=0.f;
        #pragma unroll
        for(int i=0;i<NLAGC;++i) acc+=__expf(-DTC*(float)(NLAGC-i))*xl[lane*21+1+i];
        ys=acc*DTC+GEOMC*x0;
    }

    unsigned short *zr=zbuf[0], *zw=zbuf[1];

    // ---- init phase: 20 steps, 2 barriers each ----
    #pragma unroll 1
    for(int m=0;m<NLAGC;++m){
        __syncthreads();                 // zr ready / gacc free
        P1();
        __syncthreads();                 // gacc ready
        float pre[2][4];
        COMBINE(pre);
        float xv=xl[s*21+1+m];
        float tv=(float)(m-NLAGC)*DTC;
        NONLIN(pre,xv,tv);
        unsigned short* tp=zr; zr=zw; zw=tp;
    }
    if(wid==0 && lane<16) xcur[lane]=xs; // x for t=0

    // ---- main phase: 100 steps, 3 barriers each ----
    #pragma unroll 1
    for(int t=0;t<NTC;++t){
        __syncthreads();                 // zr/xcur(prev) consumed, gacc free
        P1();
        __syncthreads();                 // gacc + pib ready
        float pre[2][4];
        COMBINE(pre);
        if(wid==0 && t>0){
            if(lane<16){
                float p0=bp0+pib[(0*2+0)*16+lane]+pib[(1*2+0)*16+lane];
                float p1=bp1+pib[(0*2+1)*16+lane]+pib[(1*2+1)*16+lane];
                p0=2.0f*sigm(p0);
                p1=2.0f*sigm(p1);
                float disc=__expf(-BETAC*(float)(t-1)*DTC);
                rew+=(__logf(fmaxf(p0*xs,0.f)+EPSC)*disc-fmaxf(-xs,0.f)*UPENC)*DTC;
                float dxv=((MU1C-RC)*p1-p0+RC)*xs+MU2C*ys;
                xs=xs+dxv*DTC+SIGC*xs*p1*dwl[lane*NTC+(t-1)];
                ys=ys*YDECC+xs*DTC;
                xcur[lane]=xs;
            }
        }
        __syncthreads();                 // xcur ready
        float xv=xcur[s];
        float tv=(float)t*DTC;
        NONLIN(pre,xv,tv);
        unsigned short* tp=zr; zr=zw; zw=tp;
    }

    // ---- epilogue: pi(h_final) -> SDE(NTC-1) + final utility ----
    __syncthreads();                     // zr (final h) ready
    if(cg==0){
        const unsigned short* zp_=zr+col*ZSTR+half*64+kg*8;
        short8v av0_=*(const short8v*)(zp_);
        short8v av1_=*(const short8v*)(zp_+32);
        f32x4 a4_={0.f,0.f,0.f,0.f};
        a4_=MFMA(av0_,bpif[0],a4_);
        a4_=MFMA(av1_,bpif[1],a4_);
        if(col<2) *(f32x4*)&pib[(half*2+col)*16+kg*4]=a4_;
    }
    __syncthreads();                     // pib ready
    if(wid==0 && lane<16){
        float p0=bp0+pib[(0*2+0)*16+lane]+pib[(1*2+0)*16+lane];
        float p1=bp1+pib[(0*2+1)*16+lane]+pib[(1*2+1)*16+lane];
        p0=2.0f*sigm(p0);
        p1=2.0f*sigm(p1);
        float disc=__expf(-BETAC*(float)(NTC-1)*DTC);
        rew+=(__logf(fmaxf(p0*xs,0.f)+EPSC)*disc-fmaxf(-xs,0.f)*UPENC)*DTC;
        float dxv=((MU1C-RC)*p1-p0+RC)*xs+MU2C*ys;
        xs=xs+dxv*DTC+SIGC*xs*p1*dwl[lane*NTC+(NTC-1)];
        ys=ys*YDECC+xs*DTC;
        rew+=__logf(fmaxf(xs+ETAC*ys,0.f)+EPSC)*(FDISCC/BETAC)-fmaxf(-xs,0.f)*UPENC;
        out[base+lane]=-rew;
    }
}

extern "C" void kernel_launch(void* const* d_in, const int* in_sizes, int n_in,
                              void* d_out, int out_size, void* d_ws, size_t ws_size,
                              hipStream_t stream){
    const float* dw  = (const float*)d_in[0];
    const float* xin = (const float*)d_in[1];
    const float* Wf  = (const float*)d_in[2];
    const float* bf  = (const float*)d_in[3];
    const float* Wi  = (const float*)d_in[4];
    const float* bi  = (const float*)d_in[5];
    const float* Wo  = (const float*)d_in[6];
    const float* bo  = (const float*)d_in[7];
    const float* Wc  = (const float*)d_in[8];
    const float* bc  = (const float*)d_in[9];
    const float* Wpi = (const float*)d_in[10];
    const float* bpi = (const float*)d_in[11];
    float* out = (float*)d_out;
    int nblk = (out_size + 15) / 16;   // 256 blocks of 1024 threads, 1/CU
    polstm<<<dim3(nblk), dim3(TPB), 0, stream>>>(dw, xin, Wf, bf, Wi, bi, Wo, bo, Wc, bc, Wpi, bpi, out);
}